// Round 6
// baseline (232.999 us; speedup 1.0000x reference)
//
#include <hip/hip_runtime.h>
#include <stdint.h>

// ---------------------------------------------------------------------------
// MultiheadMaskedAttention (B=2, S=2048, H=1024, 16 heads x d=64)
// R6: LDS-free attention inner loop. Compute S^T = K*Q^T (operand swap);
// S^T's C-frag (q=lane&15, s=quad*4+r) IS the B-operand layout of
// v_mfma_f32_16x16x16_bf16 (k=quad*4+j, n=lane&15), so exp+pack feeds PV
// directly: O^T[d][q] += V^T-frag (A) x P^T-frag (B). No ds_write/ds_read
// on the critical path. l via all-ones-A MFMA on the same P^T frags.
// ---------------------------------------------------------------------------

typedef __bf16 bf16;
typedef __attribute__((ext_vector_type(8))) __bf16 bf16x8;
typedef __attribute__((ext_vector_type(4))) __bf16 bf16x4;
typedef __attribute__((ext_vector_type(4))) float floatx4;
typedef __attribute__((ext_vector_type(4))) short short4v;

#define SCL 0.18033688011112042f  // (1/sqrt(64)) * log2(e)

__device__ __forceinline__ floatx4 mfma_bf16(bf16x8 a, bf16x8 b, floatx4 c) {
  // A: m=lane&15, k=quad*8+j ; B: n=lane&15, k=quad*8+j ; D: n=lane&15,
  // m=quad*4+reg  [verified m89/m91]
  return __builtin_amdgcn_mfma_f32_16x16x32_bf16(a, b, c, 0, 0, 0);
}
__device__ __forceinline__ floatx4 mfma16(short4v a, short4v b, floatx4 c) {
  // 16x16x16 bf16 (CDNA2 "_1k", carried forward): A: m=lane&15, k=quad*4+j;
  // B: k=quad*4+j, n=lane&15; D: n=lane&15, m=quad*4+reg
  return __builtin_amdgcn_mfma_f32_16x16x16bf16_1k(a, b, c, 0, 0, 0);
}

__device__ __forceinline__ void cp_g2l_16(const bf16* g, bf16* l) {
  __builtin_amdgcn_global_load_lds(
      (const __attribute__((address_space(1))) void*)g,
      (__attribute__((address_space(3))) void*)l, 16, 0, 0);
}

// ---- merged prep: cast x -> bf16 ; cast+transpose w_qkv, w_o ----
__global__ __launch_bounds__(256) void prep_kernel(
    const float* __restrict__ x, bf16* __restrict__ xb,
    const float* __restrict__ w_qkv, bf16* __restrict__ wqkvt,
    const float* __restrict__ w_o, bf16* __restrict__ wot) {
  const int b = blockIdx.x;
  const int tid = threadIdx.x;
  if (b < 4096) {
    const int i = (b * 256 + tid) * 4;
    floatx4 v = *(const floatx4*)(x + i);
    bf16x4 o;
    o[0] = (bf16)v[0]; o[1] = (bf16)v[1]; o[2] = (bf16)v[2]; o[3] = (bf16)v[3];
    *(bf16x4*)(xb + i) = o;
    return;
  }
  __shared__ float tile[32][33];
  const float* W; bf16* Wt; int K, N, n0, k0;
  if (b < 7168) {
    const int bb = b - 4096;
    W = w_qkv; Wt = wqkvt; K = 1024; N = 3072;
    n0 = (bb % 96) * 32; k0 = (bb / 96) * 32;
  } else {
    const int bb = b - 7168;
    W = w_o; Wt = wot; K = 1024; N = 1024;
    n0 = (bb & 31) * 32; k0 = (bb >> 5) * 32;
  }
  const int tx = tid & 31, ty = tid >> 5;
  for (int i = 0; i < 4; ++i)
    tile[ty + 8 * i][tx] = W[(size_t)(k0 + ty + 8 * i) * N + n0 + tx];
  __syncthreads();
  for (int i = 0; i < 4; ++i)
    Wt[(size_t)(n0 + ty + 8 * i) * K + k0 + tx] = (bf16)tile[tx][ty + 8 * i];
}

// ---- GEMM: C = A(M x K bf16 rm) * Bt(N x K bf16 rm)^T + bias ----
template <int MODE, int MI>
__global__ __launch_bounds__(256, 3) void gemm_bt_kernel(
    const bf16* __restrict__ A, const bf16* __restrict__ Bt,
    const float* __restrict__ bias, float* __restrict__ outF,
    bf16* __restrict__ qb, bf16* __restrict__ kb, bf16* __restrict__ vtb,
    int N, int K) {
  constexpr int BM = MI * 32;
  __shared__ bf16 As[BM * 32];
  __shared__ bf16 Bs[128 * 32];
  const int tid = threadIdx.x;
  const int w = tid >> 6, lane = tid & 63;
  const int l16 = lane & 15, quad = lane >> 4;
  const int m0 = blockIdx.y * BM, n0 = blockIdx.x * 128;
  const int wm = (w & 1) * (BM / 2), wn = (w >> 1) * 64;

  const int arow = w * (BM / 4) + (lane >> 2);
  const int acol = (lane & 3) * 8;
  const bf16* Ag = A + (size_t)(m0 + arow) * K + acol;
  bf16* Al = As + arow * 32 + acol;
  const int brow = w * 32 + (lane >> 2);
  const bf16* Bg = Bt + (size_t)(n0 + brow) * K + acol;
  bf16* Bl = Bs + brow * 32 + acol;

  floatx4 acc[MI][4];
#pragma unroll
  for (int i = 0; i < MI; ++i)
#pragma unroll
    for (int j = 0; j < 4; ++j) acc[i][j] = (floatx4){0.f, 0.f, 0.f, 0.f};

  for (int k0 = 0; k0 < K; k0 += 32) {
    __syncthreads();
    cp_g2l_16(Ag + k0, Al);
    if (MI == 4) cp_g2l_16(Ag + (size_t)16 * K + k0, Al + 16 * 32);
    cp_g2l_16(Bg + k0, Bl);
    cp_g2l_16(Bg + (size_t)16 * K + k0, Bl + 16 * 32);
    __syncthreads();
    bf16x8 af[MI], bfr[4];
#pragma unroll
    for (int i = 0; i < MI; ++i)
      af[i] = *(const bf16x8*)(&As[(wm + i * 16 + l16) * 32 + quad * 8]);
#pragma unroll
    for (int j = 0; j < 4; ++j)
      bfr[j] = *(const bf16x8*)(&Bs[(wn + j * 16 + l16) * 32 + quad * 8]);
#pragma unroll
    for (int i = 0; i < MI; ++i)
#pragma unroll
      for (int j = 0; j < 4; ++j)
        acc[i][j] = mfma_bf16(af[i], bfr[j], acc[i][j]);
  }

#pragma unroll
  for (int i = 0; i < MI; ++i)
#pragma unroll
    for (int j = 0; j < 4; ++j) {
      const int nn = n0 + wn + j * 16 + l16;
      const float bv = bias[nn];
      const int mbase = m0 + wm + i * 16 + quad * 4;
      if (MODE == 1) {
#pragma unroll
        for (int r = 0; r < 4; ++r)
          outF[(size_t)(mbase + r) * N + nn] = acc[i][j][r] + bv;
      } else {
        const int which = nn >> 10;  // uniform per block
        const int rem = nn & 1023;
        const int h = rem >> 6, d = rem & 63;
        const int b = mbase >> 11, s = mbase & 2047;
        const size_t bh = (size_t)(b * 16 + h);
        if (which == 2) {
          bf16x4 pk;
#pragma unroll
          for (int r = 0; r < 4; ++r) pk[r] = (bf16)(acc[i][j][r] + bv);
          *(bf16x4*)(vtb + (bh * 64 + d) * 2048 + s) = pk;
        } else if (which == 0) {
#pragma unroll
          for (int r = 0; r < 4; ++r)
            qb[(bh * 2048 + s + r) * 64 + d] = (bf16)((acc[i][j][r] + bv) * SCL);
        } else {
#pragma unroll
          for (int r = 0; r < 4; ++r)
            kb[(bh * 2048 + s + r) * 64 + d] = (bf16)(acc[i][j][r] + bv);
        }
      }
    }
}

// ---- Flash attention, causal, max-free softmax, LDS-free inner loop. ----
// 2048 blocks: block = (head, 32-row q-tile), big tiles first; 4 waves split
// KV strided. S^T = K*Q^T; P^T = exp2(S^T) packed in-register as the
// B-operand of 16x16x16 PV MFMAs (A = V^T frags) -> O^T[d][q].
__global__ __launch_bounds__(256, 3) void attn_kernel(
    const bf16* __restrict__ Qb, const bf16* __restrict__ Kb,
    const bf16* __restrict__ Vtb, bf16* __restrict__ attnb) {
  __shared__ __align__(16) float Cb[2 * 2304];  // 2 combine slots (18.4 KB)
  const int bid = blockIdx.x;
  const int bh = (bid & 7) * 4 + ((bid >> 3) & 3);  // 4 heads per XCD
  const int qt = 63 - (bid >> 5);                   // big q-tiles first
  const int tid = threadIdx.x;
  const int w = tid >> 6, lane = tid & 63;
  const int l16 = lane & 15, quad = lane >> 4;
  const int q0 = qt * 32;
  const int b = bh >> 4, h = bh & 15;
  const bf16* Qh = Qb + (size_t)bh * 2048 * 64;
  const bf16* Kh = Kb + (size_t)bh * 2048 * 64;
  const bf16* Vh = Vtb + (size_t)bh * 64 * 2048;

  const int nt = (qt >> 1) + 1;  // KV tiles for this q-tile
  const int tdiag = nt - 1;

  // Q frags (B-operand of S^T: n=l16=qrow, k=quad*8+j=d) — same loads as ever
  bf16x8 qf[2][2];
#pragma unroll
  for (int mb = 0; mb < 2; ++mb)
#pragma unroll
    for (int kq = 0; kq < 2; ++kq)
      qf[mb][kq] = *(const bf16x8*)(Qh + (size_t)(q0 + mb * 16 + l16) * 64 +
                                    kq * 32 + quad * 8);
  short4v onesA;
#pragma unroll
  for (int j = 0; j < 4; ++j) onesA[j] = (short)0x3F80;  // bf16 1.0

  // O^T accumulators: [md][mb], lane holds q=l16, d=md*16+quad*4+r
  floatx4 O[4][2];
  floatx4 Ol[2];  // l replicated across m rows
#pragma unroll
  for (int md = 0; md < 4; ++md)
#pragma unroll
    for (int mb = 0; mb < 2; ++mb) O[md][mb] = (floatx4){0.f, 0.f, 0.f, 0.f};
  Ol[0] = (floatx4){0.f, 0.f, 0.f, 0.f};
  Ol[1] = (floatx4){0.f, 0.f, 0.f, 0.f};

  // prologue K frags for t = w (A-operand of S^T: m=l16=kcol, k=quad*8+j=d)
  bf16x8 kf[4][2];
  {
    const bf16* Kt = Kh + (size_t)(w < nt ? w : 0) * 64 * 64;
#pragma unroll
    for (int nk = 0; nk < 4; ++nk)
#pragma unroll
      for (int kq = 0; kq < 2; ++kq)
        kf[nk][kq] =
            *(const bf16x8*)(Kt + (nk * 16 + l16) * 64 + kq * 32 + quad * 8);
  }

  for (int t = w; t < nt; t += 4) {
    const bool diag = (t == tdiag);

    // V^T A-frags: vf[md][nk] = Vt[d=md*16+l16][s=t*64+nk*16+quad*4+j]
    short4v vf[4][4];
#pragma unroll
    for (int md = 0; md < 4; ++md)
#pragma unroll
      for (int nk = 0; nk < 4; ++nk)
        vf[md][nk] = *(const short4v*)(Vh + (size_t)(md * 16 + l16) * 2048 +
                                       t * 64 + nk * 16 + quad * 4);

    // ---- mb0: S^T -> exp/pack -> l + PV ----
    {
      floatx4 sf[4];
#pragma unroll
      for (int nk = 0; nk < 4; ++nk) {
        floatx4 a = (floatx4){0.f, 0.f, 0.f, 0.f};
        a = mfma_bf16(kf[nk][0], qf[0][0], a);
        a = mfma_bf16(kf[nk][1], qf[0][1], a);
        sf[nk] = a;
      }
      short4v Pt[4];
#pragma unroll
      for (int nk = 0; nk < 4; ++nk)
#pragma unroll
        for (int r = 0; r < 4; ++r) {
          float s = sf[nk][r];
          if (diag) {
            const int kc = t * 64 + nk * 16 + quad * 4 + r;
            const int qrow = q0 + l16;
            s = (kc <= qrow) ? s : -1e30f;
          }
          Pt[nk][r] = __builtin_bit_cast(short, (bf16)__builtin_amdgcn_exp2f(s));
        }
#pragma unroll
      for (int nk = 0; nk < 4; ++nk) Ol[0] = mfma16(onesA, Pt[nk], Ol[0]);
#pragma unroll
      for (int md = 0; md < 4; ++md)
#pragma unroll
        for (int nk = 0; nk < 4; ++nk)
          O[md][0] = mfma16(vf[md][nk], Pt[nk], O[md][0]);
    }
    // ---- mb1: S^T (last use of kf) ----
    floatx4 sg[4];
#pragma unroll
    for (int nk = 0; nk < 4; ++nk) {
      floatx4 a = (floatx4){0.f, 0.f, 0.f, 0.f};
      a = mfma_bf16(kf[nk][0], qf[1][0], a);
      a = mfma_bf16(kf[nk][1], qf[1][1], a);
      sg[nk] = a;
    }
    // in-place prefetch of next K tile (t+4, clamped; unused on last iter)
    {
      const int tn = (t + 4 < nt) ? (t + 4) : 0;
      const bf16* Kt = Kh + (size_t)tn * 64 * 64;
#pragma unroll
      for (int nk = 0; nk < 4; ++nk)
#pragma unroll
        for (int kq = 0; kq < 2; ++kq)
          kf[nk][kq] =
              *(const bf16x8*)(Kt + (nk * 16 + l16) * 64 + kq * 32 + quad * 8);
    }
    // ---- mb1: exp/pack -> l + PV ----
    {
      short4v Pt[4];
#pragma unroll
      for (int nk = 0; nk < 4; ++nk)
#pragma unroll
        for (int r = 0; r < 4; ++r) {
          float s = sg[nk][r];
          if (diag) {
            const int kc = t * 64 + nk * 16 + quad * 4 + r;
            const int qrow = q0 + 16 + l16;
            s = (kc <= qrow) ? s : -1e30f;
          }
          Pt[nk][r] = __builtin_bit_cast(short, (bf16)__builtin_amdgcn_exp2f(s));
        }
#pragma unroll
      for (int nk = 0; nk < 4; ++nk) Ol[1] = mfma16(onesA, Pt[nk], Ol[1]);
#pragma unroll
      for (int md = 0; md < 4; ++md)
#pragma unroll
        for (int nk = 0; nk < 4; ++nk)
          O[md][1] = mfma16(vf[md][nk], Pt[nk], O[md][1]);
    }
  }

  // ---- combine 4 partials (pure sums): tree through 2 LDS slots ----
  // slot layout: frag f=md*2+mb at floats [(f*64+lane)*4 ..+3]; l at 2048+mb*64+lane
  __syncthreads();
  if (w >= 2) {
    float* S = Cb + (w - 2) * 2304;
#pragma unroll
    for (int md = 0; md < 4; ++md)
#pragma unroll
      for (int mb = 0; mb < 2; ++mb)
        *(floatx4*)(S + ((md * 2 + mb) * 64 + lane) * 4) = O[md][mb];
    S[2048 + 0 * 64 + lane] = Ol[0][0];
    S[2048 + 1 * 64 + lane] = Ol[1][0];
  }
  __syncthreads();
  if (w < 2) {
    const float* S = Cb + w * 2304;
#pragma unroll
    for (int md = 0; md < 4; ++md)
#pragma unroll
      for (int mb = 0; mb < 2; ++mb)
        O[md][mb] += *(const floatx4*)(S + ((md * 2 + mb) * 64 + lane) * 4);
    Ol[0][0] += S[2048 + 0 * 64 + lane];
    Ol[1][0] += S[2048 + 1 * 64 + lane];
  }
  __syncthreads();
  if (w == 1) {
#pragma unroll
    for (int md = 0; md < 4; ++md)
#pragma unroll
      for (int mb = 0; mb < 2; ++mb)
        *(floatx4*)(Cb + ((md * 2 + mb) * 64 + lane) * 4) = O[md][mb];
    Cb[2048 + 0 * 64 + lane] = Ol[0][0];
    Cb[2048 + 1 * 64 + lane] = Ol[1][0];
  }
  __syncthreads();
  if (w == 0) {
#pragma unroll
    for (int md = 0; md < 4; ++md)
#pragma unroll
      for (int mb = 0; mb < 2; ++mb)
        O[md][mb] += *(const floatx4*)(Cb + ((md * 2 + mb) * 64 + lane) * 4);
    Ol[0][0] += Cb[2048 + 0 * 64 + lane];
    Ol[1][0] += Cb[2048 + 1 * 64 + lane];
    // epilogue: lane holds q=l16 fixed; d=md*16+quad*4+r -> 8B stores
#pragma unroll
    for (int mb = 0; mb < 2; ++mb) {
      const float inv = 1.f / Ol[mb][0];
      const size_t rowbase = ((size_t)(b * 2048 + q0 + mb * 16 + l16)) * 1024;
#pragma unroll
      for (int md = 0; md < 4; ++md) {
        bf16x4 pk;
#pragma unroll
        for (int r = 0; r < 4; ++r) pk[r] = (bf16)(O[md][mb][r] * inv);
        *(bf16x4*)(attnb + rowbase + h * 64 + md * 16 + quad * 4) = pk;
      }
    }
  }
}

// ---------------------------------------------------------------------------
extern "C" void kernel_launch(void* const* d_in, const int* in_sizes, int n_in,
                              void* d_out, int out_size, void* d_ws, size_t ws_size,
                              hipStream_t stream) {
  const float* x     = (const float*)d_in[0];  // (2,2048,1024)
  const float* w_qkv = (const float*)d_in[1];  // (1024,3072)
  const float* b_qkv = (const float*)d_in[2];  // (3072)
  const float* w_o   = (const float*)d_in[3];  // (1024,1024)
  const float* b_o   = (const float*)d_in[4];  // (1024)
  float* out = (float*)d_out;                  // (2,2048,1024) fp32

  char* ws = (char*)d_ws;
  bf16* xb    = (bf16*)ws; ws += (size_t)4096 * 1024 * 2;
  bf16* wqkvt = (bf16*)ws; ws += (size_t)3072 * 1024 * 2;
  bf16* wot   = (bf16*)ws; ws += (size_t)1024 * 1024 * 2;
  bf16* qb    = (bf16*)ws; ws += (size_t)32 * 2048 * 64 * 2;
  bf16* kb    = (bf16*)ws; ws += (size_t)32 * 2048 * 64 * 2;
  bf16* vtb   = (bf16*)ws; ws += (size_t)32 * 2048 * 64 * 2;  // (bh,64,S)
  bf16* attnb = (bf16*)ws; ws += (size_t)4096 * 1024 * 2;

  prep_kernel<<<8192, 256, 0, stream>>>(x, xb, w_qkv, wqkvt, w_o, wot);
  gemm_bt_kernel<0, 4><<<dim3(24, 32), 256, 0, stream>>>(
      xb, wqkvt, b_qkv, nullptr, qb, kb, vtb, 3072, 1024);
  attn_kernel<<<2048, 256, 0, stream>>>(qb, kb, vtb, attnb);
  gemm_bt_kernel<1, 2><<<dim3(8, 64), 256, 0, stream>>>(
      attnb, wot, b_o, out, nullptr, nullptr, nullptr, 1024, 1024);
}

// Round 7
// 189.092 us; speedup vs baseline: 1.2322x; 1.2322x over previous
//
#include <hip/hip_runtime.h>
#include <stdint.h>

// ---------------------------------------------------------------------------
// MultiheadMaskedAttention (B=2, S=2048, H=1024, 16 heads x d=64)
// R7: attention with block-shared KV tiles staged via global_load_lds into
// unpadded 64x64 LDS tiles, made conflict-free by a source-side rotation
// swizzle (LDS[row][slot] = tile[row][(slot-row)&7], 16B chunks). 4 waves
// share each staged tile (4x VMEM cut vs R4-R6). Max-free softmax, raw
// exp2, ones-MFMA l, R4's verified P C->A LDS round-trip. No KV split, no
// combine tree. GEMMs/prep unchanged from R6.
// ---------------------------------------------------------------------------

typedef __bf16 bf16;
typedef __attribute__((ext_vector_type(8))) __bf16 bf16x8;
typedef __attribute__((ext_vector_type(4))) __bf16 bf16x4;
typedef __attribute__((ext_vector_type(4))) float floatx4;

#define SCL 0.18033688011112042f  // (1/sqrt(64)) * log2(e)

__device__ __forceinline__ floatx4 mfma_bf16(bf16x8 a, bf16x8 b, floatx4 c) {
  // A: m=lane&15, k=quad*8+j ; B: n=lane&15, k=quad*8+j ; D: n=lane&15,
  // m=quad*4+reg  [verified m89/m91]
  return __builtin_amdgcn_mfma_f32_16x16x32_bf16(a, b, c, 0, 0, 0);
}

__device__ __forceinline__ void cp_g2l_16(const bf16* g, bf16* l) {
  // async global->LDS, 16B/lane; LDS dest = wave-uniform base + lane*16
  __builtin_amdgcn_global_load_lds(
      (const __attribute__((address_space(1))) void*)g,
      (__attribute__((address_space(3))) void*)l, 16, 0, 0);
}

// ---- merged prep: cast x -> bf16 ; cast+transpose w_qkv, w_o ----
__global__ __launch_bounds__(256) void prep_kernel(
    const float* __restrict__ x, bf16* __restrict__ xb,
    const float* __restrict__ w_qkv, bf16* __restrict__ wqkvt,
    const float* __restrict__ w_o, bf16* __restrict__ wot) {
  const int b = blockIdx.x;
  const int tid = threadIdx.x;
  if (b < 4096) {
    const int i = (b * 256 + tid) * 4;
    floatx4 v = *(const floatx4*)(x + i);
    bf16x4 o;
    o[0] = (bf16)v[0]; o[1] = (bf16)v[1]; o[2] = (bf16)v[2]; o[3] = (bf16)v[3];
    *(bf16x4*)(xb + i) = o;
    return;
  }
  __shared__ float tile[32][33];
  const float* W; bf16* Wt; int K, N, n0, k0;
  if (b < 7168) {
    const int bb = b - 4096;
    W = w_qkv; Wt = wqkvt; K = 1024; N = 3072;
    n0 = (bb % 96) * 32; k0 = (bb / 96) * 32;
  } else {
    const int bb = b - 7168;
    W = w_o; Wt = wot; K = 1024; N = 1024;
    n0 = (bb & 31) * 32; k0 = (bb >> 5) * 32;
  }
  const int tx = tid & 31, ty = tid >> 5;
  for (int i = 0; i < 4; ++i)
    tile[ty + 8 * i][tx] = W[(size_t)(k0 + ty + 8 * i) * N + n0 + tx];
  __syncthreads();
  for (int i = 0; i < 4; ++i)
    Wt[(size_t)(n0 + ty + 8 * i) * K + k0 + tx] = (bf16)tile[tx][ty + 8 * i];
}

// ---- GEMM: C = A(M x K bf16 rm) * Bt(N x K bf16 rm)^T + bias ----
template <int MODE, int MI>
__global__ __launch_bounds__(256, 3) void gemm_bt_kernel(
    const bf16* __restrict__ A, const bf16* __restrict__ Bt,
    const float* __restrict__ bias, float* __restrict__ outF,
    bf16* __restrict__ qb, bf16* __restrict__ kb, bf16* __restrict__ vtb,
    int N, int K) {
  constexpr int BM = MI * 32;
  __shared__ bf16 As[BM * 32];
  __shared__ bf16 Bs[128 * 32];
  const int tid = threadIdx.x;
  const int w = tid >> 6, lane = tid & 63;
  const int l16 = lane & 15, quad = lane >> 4;
  const int m0 = blockIdx.y * BM, n0 = blockIdx.x * 128;
  const int wm = (w & 1) * (BM / 2), wn = (w >> 1) * 64;

  const int arow = w * (BM / 4) + (lane >> 2);
  const int acol = (lane & 3) * 8;
  const bf16* Ag = A + (size_t)(m0 + arow) * K + acol;
  bf16* Al = As + arow * 32 + acol;
  const int brow = w * 32 + (lane >> 2);
  const bf16* Bg = Bt + (size_t)(n0 + brow) * K + acol;
  bf16* Bl = Bs + brow * 32 + acol;

  floatx4 acc[MI][4];
#pragma unroll
  for (int i = 0; i < MI; ++i)
#pragma unroll
    for (int j = 0; j < 4; ++j) acc[i][j] = (floatx4){0.f, 0.f, 0.f, 0.f};

  for (int k0 = 0; k0 < K; k0 += 32) {
    __syncthreads();
    cp_g2l_16(Ag + k0, Al);
    if (MI == 4) cp_g2l_16(Ag + (size_t)16 * K + k0, Al + 16 * 32);
    cp_g2l_16(Bg + k0, Bl);
    cp_g2l_16(Bg + (size_t)16 * K + k0, Bl + 16 * 32);
    __syncthreads();
    bf16x8 af[MI], bfr[4];
#pragma unroll
    for (int i = 0; i < MI; ++i)
      af[i] = *(const bf16x8*)(&As[(wm + i * 16 + l16) * 32 + quad * 8]);
#pragma unroll
    for (int j = 0; j < 4; ++j)
      bfr[j] = *(const bf16x8*)(&Bs[(wn + j * 16 + l16) * 32 + quad * 8]);
#pragma unroll
    for (int i = 0; i < MI; ++i)
#pragma unroll
      for (int j = 0; j < 4; ++j)
        acc[i][j] = mfma_bf16(af[i], bfr[j], acc[i][j]);
  }

#pragma unroll
  for (int i = 0; i < MI; ++i)
#pragma unroll
    for (int j = 0; j < 4; ++j) {
      const int nn = n0 + wn + j * 16 + l16;
      const float bv = bias[nn];
      const int mbase = m0 + wm + i * 16 + quad * 4;
      if (MODE == 1) {
#pragma unroll
        for (int r = 0; r < 4; ++r)
          outF[(size_t)(mbase + r) * N + nn] = acc[i][j][r] + bv;
      } else {
        const int which = nn >> 10;  // uniform per block
        const int rem = nn & 1023;
        const int h = rem >> 6, d = rem & 63;
        const int b = mbase >> 11, s = mbase & 2047;
        const size_t bh = (size_t)(b * 16 + h);
        if (which == 2) {
          bf16x4 pk;
#pragma unroll
          for (int r = 0; r < 4; ++r) pk[r] = (bf16)(acc[i][j][r] + bv);
          *(bf16x4*)(vtb + (bh * 64 + d) * 2048 + s) = pk;
        } else if (which == 0) {
#pragma unroll
          for (int r = 0; r < 4; ++r)
            qb[(bh * 2048 + s + r) * 64 + d] = (bf16)((acc[i][j][r] + bv) * SCL);
        } else {
#pragma unroll
          for (int r = 0; r < 4; ++r)
            kb[(bh * 2048 + s + r) * 64 + d] = (bf16)(acc[i][j][r] + bv);
        }
      }
    }
}

// ---- Flash attention, causal: block-shared KV via global_load_lds. ----
// 512 blocks: block = (head, 128-row q-block), big q-blocks first. Wave w
// owns rows q0 = 128*qb + 32*w. All 4 waves share each staged 64-row KV
// tile. Swizzle: LDS[row][slot] holds tile[row][(slot-row)&7] (16B chunks)
// so frag reads hit all 32 banks despite the unpadded-g2l layout.
__global__ __launch_bounds__(256, 3) void attn_kernel(
    const bf16* __restrict__ Qb, const bf16* __restrict__ Kb,
    const bf16* __restrict__ Vtb, bf16* __restrict__ attnb) {
  __shared__ bf16 Ks[4096];        // 64 s-rows x 64 d (swizzled chunks)
  __shared__ bf16 Vs[4096];        // 64 d-rows x 64 s (swizzled chunks)
  __shared__ bf16 Ps[4 * 2368];    // per-wave padded P (R4 layout)
  const int bid = blockIdx.x;
  const int bh = (bid & 7) * 4 + ((bid >> 3) & 3);  // 4 heads per XCD
  const int qblk = 15 - (bid >> 5);                 // big q-blocks first
  const int tid = threadIdx.x;
  const int w = tid >> 6, lane = tid & 63;
  const int l16 = lane & 15, quad = lane >> 4;
  const int q0 = qblk * 128 + w * 32;
  const int b = bh >> 4, h = bh & 15;
  const bf16* Qh = Qb + (size_t)bh * 2048 * 64;
  const bf16* Kh = Kb + (size_t)bh * 2048 * 64;
  const bf16* Vh = Vtb + (size_t)bh * 64 * 2048;
  bf16* Pw = Ps + w * 2368;
  const int pw_wr = quad * 288 + (quad >> 1) * 16 + l16;    // row=quad*4+r
  const int pw_rd = l16 * 72 + (l16 >> 3) * 16 + quad * 8;  // row=l16

  const int nt = 2 * qblk + 2;   // KV tiles for this q-block
  const int wdiag = q0 >> 6;     // this wave's diagonal tile

  // staging chunk ids (16B chunks, 512 per tile): this thread copies c0,c1
  const int c0 = tid, c1 = 256 + tid;
  // K source element offset within tile for dest chunk c:
  //   row = c>>3, slot = c&7 -> src chunk (slot-row)&7
  const int ksrc0 = (c0 >> 3) * 64 + (((c0 & 7) - (c0 >> 3)) & 7) * 8;
  const int ksrc1 = (c1 >> 3) * 64 + (((c1 & 7) - (c1 >> 3)) & 7) * 8;
  // V source offset (row d has global stride 2048): + t*64 at runtime
  const int vsrc0 = (c0 >> 3) * 2048 + (((c0 & 7) - (c0 >> 3)) & 7) * 8;
  const int vsrc1 = (c1 >> 3) * 2048 + (((c1 & 7) - (c1 >> 3)) & 7) * 8;
  bf16* kdst0 = Ks + c0 * 8; bf16* kdst1 = Ks + c1 * 8;
  bf16* vdst0 = Vs + c0 * 8; bf16* vdst1 = Vs + c1 * 8;

  // Q frags held in registers all kernel
  bf16x8 qf[2][2];
#pragma unroll
  for (int mb = 0; mb < 2; ++mb)
#pragma unroll
    for (int kq = 0; kq < 2; ++kq)
      qf[mb][kq] = *(const bf16x8*)(Qh + (size_t)(q0 + mb * 16 + l16) * 64 +
                                    kq * 32 + quad * 8);
  bf16x8 ones;
#pragma unroll
  for (int j = 0; j < 8; ++j) ones[j] = (bf16)1.0f;

  floatx4 O[2][4], Ol[2];
#pragma unroll
  for (int mb = 0; mb < 2; ++mb) {
#pragma unroll
    for (int nd = 0; nd < 4; ++nd) O[mb][nd] = (floatx4){0.f, 0.f, 0.f, 0.f};
    Ol[mb] = (floatx4){0.f, 0.f, 0.f, 0.f};
  }

  for (int t = 0; t < nt; ++t) {
    __syncthreads();  // all waves done reading previous Ks/Vs
    {
      const bf16* KtG = Kh + (size_t)t * 4096;
      const bf16* VtG = Vh + t * 64;
      cp_g2l_16(KtG + ksrc0, kdst0);
      cp_g2l_16(KtG + ksrc1, kdst1);
      cp_g2l_16(VtG + vsrc0, vdst0);
      cp_g2l_16(VtG + vsrc1, vdst1);
    }
    __syncthreads();  // staging complete (vmcnt drained at barrier)

    if (t > wdiag) continue;  // fully-masked tile for this wave
    const bool diag = (t == wdiag);

    // K frags from LDS (swizzled addrs; loop-invariant)
    bf16x8 kf[4][2];
#pragma unroll
    for (int nk = 0; nk < 4; ++nk)
#pragma unroll
      for (int kq = 0; kq < 2; ++kq) {
        const int row = nk * 16 + l16;
        kf[nk][kq] = *(const bf16x8*)(
            &Ks[row * 64 + ((kq * 4 + quad + row) & 7) * 8]);
      }

    // ---- mb0: QK -> mask -> exp -> P write ----
    {
      floatx4 sf[4];
#pragma unroll
      for (int nk = 0; nk < 4; ++nk) {
        floatx4 a = (floatx4){0.f, 0.f, 0.f, 0.f};
        a = mfma_bf16(qf[0][0], kf[nk][0], a);
        a = mfma_bf16(qf[0][1], kf[nk][1], a);
        sf[nk] = a;
      }
#pragma unroll
      for (int nk = 0; nk < 4; ++nk)
#pragma unroll
        for (int r = 0; r < 4; ++r) {
          float s = sf[nk][r];
          if (diag) {
            const int kc = t * 64 + nk * 16 + l16;
            const int qrow = q0 + quad * 4 + r;
            s = (kc <= qrow) ? s : -1e30f;
          }
          Pw[pw_wr + r * 72 + nk * 16] = (bf16)__builtin_amdgcn_exp2f(s);
        }
    }
    // ---- mb1: QK (last use of kf) -> mask -> exp -> P write ----
    floatx4 sg[4];
#pragma unroll
    for (int nk = 0; nk < 4; ++nk) {
      floatx4 a = (floatx4){0.f, 0.f, 0.f, 0.f};
      a = mfma_bf16(qf[1][0], kf[nk][0], a);
      a = mfma_bf16(qf[1][1], kf[nk][1], a);
      sg[nk] = a;
    }
    // V frags from LDS (kf regs reusable; latency hidden under exp below)
    bf16x8 vf[4][2];
#pragma unroll
    for (int nd = 0; nd < 4; ++nd)
#pragma unroll
      for (int kq = 0; kq < 2; ++kq) {
        const int row = nd * 16 + l16;
        vf[nd][kq] = *(const bf16x8*)(
            &Vs[row * 64 + ((kq * 4 + quad + row) & 7) * 8]);
      }
#pragma unroll
    for (int nk = 0; nk < 4; ++nk)
#pragma unroll
      for (int r = 0; r < 4; ++r) {
        float s = sg[nk][r];
        if (diag) {
          const int kc = t * 64 + nk * 16 + l16;
          const int qrow = q0 + 16 + quad * 4 + r;
          s = (kc <= qrow) ? s : -1e30f;
        }
        Pw[pw_wr + 1184 + r * 72 + nk * 16] = (bf16)__builtin_amdgcn_exp2f(s);
      }

    // ---- P C-layout -> A-layout (per-wave LDS); O += P V; l += P * 1 ----
#pragma unroll
    for (int mb = 0; mb < 2; ++mb) {
      bf16x8 pf[2];
      pf[0] = *(const bf16x8*)(&Pw[pw_rd + mb * 1184]);
      pf[1] = *(const bf16x8*)(&Pw[pw_rd + mb * 1184 + 32]);
#pragma unroll
      for (int nd = 0; nd < 4; ++nd) {
        floatx4 o = O[mb][nd];
        o = mfma_bf16(pf[0], vf[nd][0], o);
        o = mfma_bf16(pf[1], vf[nd][1], o);
        O[mb][nd] = o;
      }
      Ol[mb] = mfma_bf16(pf[0], ones, Ol[mb]);
      Ol[mb] = mfma_bf16(pf[1], ones, Ol[mb]);
    }
  }

  // epilogue: each wave owns its 32 rows outright (no combine)
#pragma unroll
  for (int mb = 0; mb < 2; ++mb)
#pragma unroll
    for (int r = 0; r < 4; ++r) {
      const int qrow = q0 + mb * 16 + quad * 4 + r;
      const float inv = 1.f / Ol[mb][r];
#pragma unroll
      for (int nd = 0; nd < 4; ++nd)
        attnb[((size_t)(b * 2048 + qrow)) * 1024 + h * 64 + nd * 16 + l16] =
            (bf16)(O[mb][nd][r] * inv);
    }
}

// ---------------------------------------------------------------------------
extern "C" void kernel_launch(void* const* d_in, const int* in_sizes, int n_in,
                              void* d_out, int out_size, void* d_ws, size_t ws_size,
                              hipStream_t stream) {
  const float* x     = (const float*)d_in[0];  // (2,2048,1024)
  const float* w_qkv = (const float*)d_in[1];  // (1024,3072)
  const float* b_qkv = (const float*)d_in[2];  // (3072)
  const float* w_o   = (const float*)d_in[3];  // (1024,1024)
  const float* b_o   = (const float*)d_in[4];  // (1024)
  float* out = (float*)d_out;                  // (2,2048,1024) fp32

  char* ws = (char*)d_ws;
  bf16* xb    = (bf16*)ws; ws += (size_t)4096 * 1024 * 2;
  bf16* wqkvt = (bf16*)ws; ws += (size_t)3072 * 1024 * 2;
  bf16* wot   = (bf16*)ws; ws += (size_t)1024 * 1024 * 2;
  bf16* qb    = (bf16*)ws; ws += (size_t)32 * 2048 * 64 * 2;
  bf16* kb    = (bf16*)ws; ws += (size_t)32 * 2048 * 64 * 2;
  bf16* vtb   = (bf16*)ws; ws += (size_t)32 * 2048 * 64 * 2;  // (bh,64,S)
  bf16* attnb = (bf16*)ws; ws += (size_t)4096 * 1024 * 2;

  prep_kernel<<<8192, 256, 0, stream>>>(x, xb, w_qkv, wqkvt, w_o, wot);
  gemm_bt_kernel<0, 4><<<dim3(24, 32), 256, 0, stream>>>(
      xb, wqkvt, b_qkv, nullptr, qb, kb, vtb, 3072, 1024);
  attn_kernel<<<512, 256, 0, stream>>>(qb, kb, vtb, attnb);
  gemm_bt_kernel<1, 2><<<dim3(8, 64), 256, 0, stream>>>(
      attnb, wot, b_o, out, nullptr, nullptr, nullptr, 1024, 1024);
}